// Round 5
// baseline (116.545 us; speedup 1.0000x reference)
//
#include <hip/hip_runtime.h>
#include <math.h>

#define NB 16
#define DIN 512
#define TT 4096
#define DCB 8
#define KC 1024
#define NW 8            // kernel A waves per block

// ws layout (floats):
// [0,4096)      w_inT[d][c]   (transposed)
// [4096,8192)   w_out[o][c]
// [8192,9216)   cb2[k]
// [9216,10240)  per-block commit partials (1024)

__global__ __launch_bounds__(512) void vq_setup(
    const float* __restrict__ in_v, const float* __restrict__ in_g,
    const float* __restrict__ out_v, const float* __restrict__ out_g,
    const float* __restrict__ cb, float* __restrict__ ws)
{
    int tid = threadIdx.x;
    float* w_inT = ws;
    float* w_out = ws + 4096;
    float* cb2   = ws + 8192;

    // --- w_in: 8 rows of 512; one wave per row ---
    {
        int c    = tid >> 6;
        int lane = tid & 63;
        const float* v = in_v + c * DIN;
        float s = 0.f;
        #pragma unroll
        for (int i = 0; i < DIN; i += 64) {
            float x = v[i + lane];
            s += x * x;
        }
        #pragma unroll
        for (int off = 32; off > 0; off >>= 1) s += __shfl_xor(s, off, 64);
        float sq = sqrtf(s);
        float g  = in_g[c];
        #pragma unroll
        for (int i = 0; i < DIN; i += 64) {
            int d = i + lane;
            w_inT[d * DCB + c] = (g * v[d]) / sq;
        }
    }
    // --- w_out: 512 rows of 8 ---
    {
        int o = tid;
        const float* v = out_v + o * DCB;
        float s = 0.f;
        #pragma unroll
        for (int c = 0; c < DCB; ++c) s += v[c] * v[c];
        float sq = sqrtf(s);
        float g  = out_g[o];
        #pragma unroll
        for (int c = 0; c < DCB; ++c) w_out[o * DCB + c] = (g * v[c]) / sq;
    }
    // --- cb2 ---
    for (int k = tid; k < KC; k += 512) {
        const float* r = cb + k * DCB;
        float s = 0.f;
        #pragma unroll
        for (int c = 0; c < DCB; ++c) s += r[c] * r[c];
        cb2[k] = s;
    }
}

// Kernel A: in-projection + codebook argmin + indices + commit partials.
// 1024 blocks x 512 threads; block = (b, 64-t chunk); wave w owns
// d in [64w,64w+64) and k in [128w,128w+128).
__global__ __launch_bounds__(512, 8) void vq_encode(
    const float* __restrict__ z, const float* __restrict__ in_b,
    const float* __restrict__ cb, const float* __restrict__ ws,
    float* __restrict__ ws_commit, float* __restrict__ out)
{
    const float* w_inT = ws;
    const float* cb2   = ws + 8192;

    __shared__ float red[NW][DCB][64];   // 16 KB
    __shared__ float sd[NW][64];         // 2 KB
    __shared__ int   si[NW][64];         // 2 KB
    __shared__ float scl[NW];

    int w    = threadIdx.x >> 6;
    int wu   = __builtin_amdgcn_readfirstlane(w);
    int lane = threadIdx.x & 63;
    int blk  = blockIdx.x;               // 0..1023
    int b    = blk >> 6;
    int t    = (blk & 63) * 64 + lane;

    const float* zp = z + (size_t)b * DIN * TT + t;

    // ---- partial in-projection over d in [wu*64, wu*64+64) ----
    float ze[DCB];
    #pragma unroll
    for (int c = 0; c < DCB; ++c) ze[c] = 0.f;

    int d0 = wu * 64;
    #pragma unroll 4
    for (int dd = 0; dd < 64; ++dd) {
        int d = d0 + dd;
        float zv = zp[(size_t)d * TT];       // 256 B/wave, coalesced
        const float* wi = w_inT + d * DCB;   // wave-uniform -> s_load
        #pragma unroll
        for (int c = 0; c < DCB; ++c) ze[c] = fmaf(wi[c], zv, ze[c]);
    }

    // ---- cross-wave reduce of ze ----
    #pragma unroll
    for (int c = 0; c < DCB; ++c) red[w][c][lane] = ze[c];
    __syncthreads();
    #pragma unroll
    for (int c = 0; c < DCB; ++c) {
        float s = 0.f;
        #pragma unroll
        for (int w2 = 0; w2 < NW; ++w2) s += red[w2][c][lane];
        ze[c] = s + in_b[c];
    }

    // ---- codebook partial argmin over k in [wu*128, wu*128+128) ----
    float enc2 = 0.f;
    #pragma unroll
    for (int c = 0; c < DCB; ++c) enc2 += ze[c] * ze[c];

    float best = 3.4e38f;
    int   bi   = 0;
    int   k0   = wu * 128;
    #pragma unroll 4
    for (int kk = 0; kk < 128; ++kk) {
        int k = k0 + kk;
        const float* r = cb + k * DCB;       // wave-uniform -> s_load_dwordx8
        float dot = 0.f;
        #pragma unroll
        for (int c = 0; c < DCB; ++c) dot = fmaf(ze[c], r[c], dot);
        float dk = (enc2 - 2.0f * dot) + cb2[k];
        if (dk < best) { best = dk; bi = k; }
    }
    sd[w][lane] = best;
    si[w][lane] = bi;
    __syncthreads();

    // ordered combine (w'=0..7, strict < keeps first min over k)
    float gbest = sd[0][lane];
    int   gbi   = si[0][lane];
    #pragma unroll
    for (int w2 = 1; w2 < NW; ++w2) {
        float d2 = sd[w2][lane];
        int   i2 = si[w2][lane];
        if (d2 < gbest) { gbest = d2; gbi = i2; }
    }

    // ---- commit loss partial: (z_e - cb[idx])^2 ----
    const float* cq = cb + (size_t)gbi * DCB;  // divergent gather, L1-resident
    float cl = 0.f;
    #pragma unroll
    for (int c = 0; c < DCB; ++c) {
        float diff = ze[c] - cq[c];
        cl = fmaf(diff, diff, cl);
    }
    #pragma unroll
    for (int off = 32; off > 0; off >>= 1) cl += __shfl_xor(cl, off, 64);
    if (lane == 0) scl[w] = cl;

    if (wu == 0) {
        // indices (as float; whole out buffer is read as fp32)
        out[(size_t)NB * DIN * TT + NB + (size_t)b * TT + t] = (float)gbi;
    }

    __syncthreads();
    if (threadIdx.x == 0) {
        float s = 0.f;
        #pragma unroll
        for (int w2 = 0; w2 < NW; ++w2) s += scl[w2];
        ws_commit[blk] = s;
    }
}

// Kernel B: out-projection, pure streaming.
// 1024 blocks x 256 threads; block = (b, o-tile 128, t-tile 256).
// lane owns 4 consecutive t (float4); wave w owns o-sub [32w,32w+32).
// Uses q = cb[idx] (differs from ze+(q-ze) by <= 1 ulp of ze).
__global__ __launch_bounds__(256) void vq_out(
    const float* __restrict__ cb, const float* __restrict__ out_b,
    const float* __restrict__ ws, float* __restrict__ out)
{
    const float* w_out = ws + 4096;
    const float* idxf  = out + (size_t)NB * DIN * TT + NB;

    int blk  = blockIdx.x;               // 0..1023
    int b    = blk >> 6;
    int rest = blk & 63;
    int o0   = (rest >> 4) * 128;        // 0,128,256,384
    int t0   = (rest & 15) * 256;
    int w    = threadIdx.x >> 6;
    int wu   = __builtin_amdgcn_readfirstlane(w);
    int lane = threadIdx.x & 63;
    int t    = t0 + 4 * lane;

    float4 iv = *(const float4*)(idxf + (size_t)b * TT + t);
    int k0 = (int)iv.x, k1 = (int)iv.y, k2 = (int)iv.z, k3 = (int)iv.w;

    // gather 4 codebook rows (32 B each) — L1-resident 32 KB table
    float4 qa0 = ((const float4*)(cb))[2 * k0],     qb0 = ((const float4*)(cb))[2 * k0 + 1];
    float4 qa1 = ((const float4*)(cb))[2 * k1],     qb1 = ((const float4*)(cb))[2 * k1 + 1];
    float4 qa2 = ((const float4*)(cb))[2 * k2],     qb2 = ((const float4*)(cb))[2 * k2 + 1];
    float4 qa3 = ((const float4*)(cb))[2 * k3],     qb3 = ((const float4*)(cb))[2 * k3 + 1];

    int ob = o0 + wu * 32;
    float* outp = out + (size_t)b * DIN * TT + t;

    #pragma unroll 4
    for (int oo = 0; oo < 32; ++oo) {
        int o = ob + oo;
        const float* wo = w_out + o * DCB;   // wave-uniform -> s_load_dwordx8
        float obias = out_b[o];              // wave-uniform -> s_load
        float a0, a1, a2, a3;
        a0 = fmaf(wo[0], qa0.x, fmaf(wo[1], qa0.y, fmaf(wo[2], qa0.z, fmaf(wo[3], qa0.w,
             fmaf(wo[4], qb0.x, fmaf(wo[5], qb0.y, fmaf(wo[6], qb0.z, wo[7] * qb0.w)))))));
        a1 = fmaf(wo[0], qa1.x, fmaf(wo[1], qa1.y, fmaf(wo[2], qa1.z, fmaf(wo[3], qa1.w,
             fmaf(wo[4], qb1.x, fmaf(wo[5], qb1.y, fmaf(wo[6], qb1.z, wo[7] * qb1.w)))))));
        a2 = fmaf(wo[0], qa2.x, fmaf(wo[1], qa2.y, fmaf(wo[2], qa2.z, fmaf(wo[3], qa2.w,
             fmaf(wo[4], qb2.x, fmaf(wo[5], qb2.y, fmaf(wo[6], qb2.z, wo[7] * qb2.w)))))));
        a3 = fmaf(wo[0], qa3.x, fmaf(wo[1], qa3.y, fmaf(wo[2], qa3.z, fmaf(wo[3], qa3.w,
             fmaf(wo[4], qb3.x, fmaf(wo[5], qb3.y, fmaf(wo[6], qb3.z, wo[7] * qb3.w)))))));
        float4 r = make_float4(a0 + obias, a1 + obias, a2 + obias, a3 + obias);
        *(float4*)(outp + (size_t)o * TT) = r;   // 1 KB/wave, contiguous
    }
}

__global__ __launch_bounds__(64) void vq_commit(
    const float* __restrict__ ws_commit, float* __restrict__ out)
{
    int b    = blockIdx.x;
    int lane = threadIdx.x;
    float s = ws_commit[b * 64 + lane];
    #pragma unroll
    for (int off = 32; off > 0; off >>= 1) s += __shfl_xor(s, off, 64);
    if (lane == 0)
        out[(size_t)NB * DIN * TT + b] = s * (1.0f / (DCB * TT));
}

extern "C" void kernel_launch(void* const* d_in, const int* in_sizes, int n_in,
                              void* d_out, int out_size, void* d_ws, size_t ws_size,
                              hipStream_t stream) {
    const float* z     = (const float*)d_in[0];
    const float* in_v  = (const float*)d_in[1];
    const float* in_g  = (const float*)d_in[2];
    const float* in_b  = (const float*)d_in[3];
    const float* out_v = (const float*)d_in[4];
    const float* out_g = (const float*)d_in[5];
    const float* out_b = (const float*)d_in[6];
    const float* cb    = (const float*)d_in[7];

    float* ws  = (float*)d_ws;
    float* out = (float*)d_out;

    vq_setup<<<1, 512, 0, stream>>>(in_v, in_g, out_v, out_g, cb, ws);
    vq_encode<<<1024, 512, 0, stream>>>(z, in_b, cb, ws, ws + 9216, out);
    vq_out<<<1024, 256, 0, stream>>>(cb, out_b, ws, out);
    vq_commit<<<NB, 64, 0, stream>>>(ws + 9216, out);
}